// Round 2
// baseline (1612.796 us; speedup 1.0000x reference)
//
#include <hip/hip_runtime.h>

#define TAGS 128
#define SEQ 1024
#define BATCH 128
#define NGRP 8          // batch groups of 16 (per direction)
#define GB 16           // batches per group

typedef __attribute__((ext_vector_type(8))) _Float16 half8;
typedef __attribute__((ext_vector_type(2))) _Float16 half2v;
typedef __attribute__((ext_vector_type(4))) float f32x4;

#define GS_BYTES ((size_t)NGRP * SEQ * 64 * 16 * 4)   // 33.5 MB of u32 (f16 pairs)

static __device__ __forceinline__ unsigned pk2u(float a, float b) {
    return __builtin_bit_cast(unsigned, __builtin_amdgcn_cvt_pkrtz(a, b));
}

// ---------------------------------------------------------------------------
// Layout (16x16x32 MFMA, 16-batch chains).
// Lane L: n = L&15 (batch col), kb = L>>4 (k-block).
// B-frag / state dword slot (sl in [0,4), d in [0,4)) at lane L holds the f16
// pair for tags u0, u0+1 with  u0 = 16*(2*sl + (d>>1)) + 4*kb + 2*(d&1).
// acc[t][r] (D[m][n], m = 16t + 4kb + r) maps straight into the B-frag slot
// (sl,d) with t = 2sl+(d>>1), r = 2(d&1) -- no cross-lane movement.
// gs memory: per (grp, i, lane): 16 dwords in slot order [sl][d].
// ---------------------------------------------------------------------------

#define EPITCH 66
__global__ __launch_bounds__(64, 1)
void exp_pack(const float* __restrict__ yp, unsigned* __restrict__ gs)
{
    __shared__ unsigned ldsT[GB * EPITCH];
    const int blk = blockIdx.x;               // grp*SEQ + i
    const int grp = blk >> 10, i = blk & (SEQ - 1);
    const int tid = threadIdx.x;
    const float* src = yp + (size_t)(grp * GB) * SEQ * TAGS + (size_t)i * TAGS;

#pragma unroll
    for (int k = 0; k < 8; ++k) {
        int f = tid + 64 * k;                 // flat float4 index in 16x32 grid
        int r = f >> 5, c = f & 31;
        const float4 v = *(const float4*)(src + (size_t)r * SEQ * TAGS + 4 * c);
        uint2 d;
        d.x = pk2u(__expf(v.x), __expf(v.y));
        d.y = pk2u(__expf(v.z), __expf(v.w));
        *(uint2*)&ldsT[r * EPITCH + 2 * c] = d;
    }
    __syncthreads();

    const int kb = tid >> 4, n = tid & 15;
    unsigned* dst = gs + ((size_t)blk * 64 + tid) * 16;
    uint2 w[8];
#pragma unroll
    for (int sl = 0; sl < 4; ++sl)
#pragma unroll
        for (int dd = 0; dd < 2; ++dd) {
            int t = 2 * sl + dd;
            int pu = 8 * t + 2 * kb;          // pair index of u0 = 16t+4kb
            w[2 * sl + dd] = *(const uint2*)&ldsT[n * EPITCH + pu];
        }
#pragma unroll
    for (int q = 0; q < 4; ++q)
        ((uint4*)dst)[q] = make_uint4(w[2 * q].x, w[2 * q].y,
                                      w[2 * q + 1].x, w[2 * q + 1].y);
}

// ---------------------------------------------------------------------------
// Main kernel: 16 blocks x 2 waves. Each block owns ONE chain; the two waves
// M-split the step: wave w computes output rows t = 4w..4w+3 (16 MFMAs) plus
// a redundant t=0 pivot chain (4 MFMAs, fixed sl order 0..3 in BOTH waves so
// q0/rn are bitwise identical -- the state halves must share one scale).
// Per step: one 8-dword-per-lane LDS exchange of the produced B-frag half,
// double-buffered (parity), ONE __syncthreads. Next step consumes own slices
// first so the ds_read latency hides under MFMA issue.
// Blocks 0-7: forward grp 0-7 (steps 1..512 -> F_512); blocks 8-15: backward
// (1023..513 -> beta_512 = V_513). Meet: Z = F_512 . V_513.
// ---------------------------------------------------------------------------
__global__ __launch_bounds__(128, 1)
void crf_seq(const unsigned* __restrict__ gs, const float* __restrict__ Ain,
             float* __restrict__ Fst, float* __restrict__ Vst,
             float* __restrict__ Cf, float* __restrict__ Cb)
{
    __shared__ uint4 xbuf[2][2][2][64];       // [parity][half][quad][lane]
    const int blk = blockIdx.x;
    const bool fwd = blk < NGRP;
    const int grp = fwd ? blk : blk - NGRP;
    const int w = threadIdx.x >> 6;           // wave id: 0 -> t 0..3, 1 -> t 4..7
    const int lane = threadIdx.x & 63;
    const int kb = lane >> 4, n = lane & 15;

    // ---- E A-frags in registers: own 4 row-blocks + pivot (t=0) ----
    auto build_frag = [&](int t, int sl) -> half8 {
        unsigned q[4];
#pragma unroll
        for (int d = 0; d < 4; ++d) {
            int v0 = 16 * (2 * sl + (d >> 1)) + 4 * kb + 2 * (d & 1);
            int m = 16 * t + n;
            float e0, e1;
            if (fwd) { e0 = __expf(Ain[v0 * TAGS + m]);
                       e1 = __expf(Ain[(v0 + 1) * TAGS + m]); }
            else     { e0 = __expf(Ain[m * TAGS + v0]);
                       e1 = __expf(Ain[m * TAGS + v0 + 1]); }
            q[d] = pk2u(e0, e1);
        }
        uint4 qv = make_uint4(q[0], q[1], q[2], q[3]);
        return __builtin_bit_cast(half8, qv);
    };
    half8 afO[4][4], af0[4];
#pragma unroll
    for (int tt = 0; tt < 4; ++tt)
#pragma unroll
        for (int sl = 0; sl < 4; ++sl)
            afO[tt][sl] = build_frag(4 * w + tt, sl);
#pragma unroll
    for (int sl = 0; sl < 4; ++sl)
        af0[sl] = build_frag(0, sl);

    // ---- init state from G_0 (fwd) / G_1023 (bwd): pack IS the B-frag ----
    uint4 pksq[4];
    {
        const uint4* g0 = (const uint4*)(gs +
            ((size_t)(grp * SEQ + (fwd ? 0 : SEQ - 1)) * 64 + lane) * 16);
#pragma unroll
        for (int k2 = 0; k2 < 4; ++k2) pksq[k2] = g0[k2];
    }
    float C = 0.f;
    f32x4 accO[4], a0;
    uint4 ghA[2], ghB[2];

    auto load_gh = [&](uint4 (&gq)[2], int idx) {
        const uint4* p = (const uint4*)(gs +
            ((size_t)(grp * SEQ + idx) * 64 + lane) * 16) + 2 * w;
        gq[0] = p[0]; gq[1] = p[1];
    };

    auto mfma_only = [&]() {
        f32x4 z = {0.f, 0.f, 0.f, 0.f};
#pragma unroll
        for (int slq = 0; slq < 4; ++slq) {
            int sl = (slq + 2 * w) & 3;       // own-produced slices first
            half8 bf = __builtin_bit_cast(half8, pksq[sl]);
#pragma unroll
            for (int tt = 0; tt < 4; ++tt)
                accO[tt] = __builtin_amdgcn_mfma_f32_16x16x32_f16(
                    afO[tt][sl], bf, slq == 0 ? z : accO[tt], 0, 0, 0);
            // pivot chain in FIXED order sl=0..3 (bitwise-equal across waves)
            half8 bfp = __builtin_bit_cast(half8, pksq[slq]);
            a0 = __builtin_amdgcn_mfma_f32_16x16x32_f16(
                af0[slq], bfp, slq == 0 ? z : a0, 0, 0, 0);
        }
    };

    // step: mfma + epi(own half) + LDS exchange (one barrier, parity dbuf)
    auto step = [&](const uint4 (&gh)[2], int pb) {
        mfma_only();
        float q0 = __shfl(a0[0], n, 64);      // D[0][n] lives in lane n
        float rn = __builtin_amdgcn_rcpf(q0) * 0.0625f;   // 2^-4 headroom
        C += __logf(q0) + 2.7725887222397812f;            // + log(16)
        const unsigned* gu = (const unsigned*)gh;
        unsigned pko[8];
#pragma unroll
        for (int s2 = 0; s2 < 2; ++s2)
#pragma unroll
            for (int d = 0; d < 4; ++d) {
                int tt = 2 * s2 + (d >> 1), r = 2 * (d & 1);
                half2v hv = __builtin_bit_cast(half2v,
                    pk2u(accO[tt][r] * rn, accO[tt][r + 1] * rn));
                half2v g2 = __builtin_bit_cast(half2v, gu[4 * s2 + d]);
                hv = hv * g2;
                pko[4 * s2 + d] = __builtin_bit_cast(unsigned, hv);
            }
        uint4 o0 = make_uint4(pko[0], pko[1], pko[2], pko[3]);
        uint4 o1 = make_uint4(pko[4], pko[5], pko[6], pko[7]);
        pksq[2 * w]     = o0;
        pksq[2 * w + 1] = o1;
        xbuf[pb][w][0][lane] = o0;            // 16B/lane contiguous: no bank conflict
        xbuf[pb][w][1][lane] = o1;
        __syncthreads();
        pksq[2 * (1 - w)]     = xbuf[pb][1 - w][0][lane];
        pksq[2 * (1 - w) + 1] = xbuf[pb][1 - w][1][lane];
    };

    if (fwd) {
        load_gh(ghA, 1); load_gh(ghB, 2);
#pragma unroll 1
        for (int j = 1; j <= 509; j += 2) {   // steps 1..510
            step(ghA, 1); load_gh(ghA, j + 2);
            step(ghB, 0); load_gh(ghB, j + 3);
        }
        step(ghA, 1);                         // step 511 (ghA = G_511)
        mfma_only();                          // peeled step 512
        {
            float q0 = __shfl(a0[0], n, 64);
            float rn = __builtin_amdgcn_rcpf(q0);
            C += __logf(q0);
            const unsigned* gu = (const unsigned*)ghB;   // G_512 own half
            const int b = grp * GB + n;
#pragma unroll
            for (int s2 = 0; s2 < 2; ++s2)
#pragma unroll
                for (int dd = 0; dd < 2; ++dd) {
                    const int tt = 2 * s2 + dd, t = 4 * w + tt;
                    half2v ga = __builtin_bit_cast(half2v, gu[4 * s2 + 2 * dd]);
                    half2v gb = __builtin_bit_cast(half2v, gu[4 * s2 + 2 * dd + 1]);
                    float4 wv;
                    wv.x = accO[tt][0] * rn * (float)ga[0];
                    wv.y = accO[tt][1] * rn * (float)ga[1];
                    wv.z = accO[tt][2] * rn * (float)gb[0];
                    wv.w = accO[tt][3] * rn * (float)gb[1];
                    *(float4*)&Fst[(size_t)b * TAGS + 16 * t + 4 * kb] = wv;
                }
            if (w == 0 && kb == 0) Cf[b] = C;
        }
    } else {
        load_gh(ghA, 1022); load_gh(ghB, 1021);
#pragma unroll 1
        for (int j = 1; j <= 507; j += 2) {   // epis G_1022..G_515
            step(ghA, 1); load_gh(ghA, 1023 - (j + 2));
            step(ghB, 0); load_gh(ghB, 1023 - (j + 3));
        }
        step(ghA, 1);                         // epi G_514
        step(ghB, 0);                         // epi G_513
        mfma_only();                          // peeled: beta_512
        {
            float q0 = __shfl(a0[0], n, 64);
            float rn = __builtin_amdgcn_rcpf(q0);
            C += __logf(q0);
            const int b = grp * GB + n;
#pragma unroll
            for (int tt = 0; tt < 4; ++tt) {
                const int t = 4 * w + tt;
                float4 wv;
                wv.x = accO[tt][0] * rn; wv.y = accO[tt][1] * rn;
                wv.z = accO[tt][2] * rn; wv.w = accO[tt][3] * rn;
                *(float4*)&Vst[(size_t)b * TAGS + 16 * t + 4 * kb] = wv;
            }
            if (w == 0 && kb == 0) Cb[b] = C;
        }
    }
}

// logZ_b = Cf + Cb + log(F_512 . V_513);  out += logZ_b / BATCH
__global__ __launch_bounds__(128, 1)
void crf_combine(const float* __restrict__ Fst, const float* __restrict__ Vst,
                 const float* __restrict__ Cf, const float* __restrict__ Cb,
                 float* __restrict__ out)
{
    int b = threadIdx.x;
    const float* f = Fst + (size_t)b * TAGS;
    const float* v = Vst + (size_t)b * TAGS;
    float s = 0.f;
#pragma unroll
    for (int u = 0; u < TAGS; ++u) s += f[u] * v[u];
    float logZ = Cf[b] + Cb[b] + __logf(s);
    atomicAdd(out, logZ * (1.0f / (float)BATCH));
}

// Gold-path score (validated): adds -score_b / BATCH
__global__ __launch_bounds__(128, 1)
void crf_score(const float* __restrict__ yp, const int* __restrict__ yt,
               const float* __restrict__ mask, const float* __restrict__ A,
               float* __restrict__ out)
{
    const int b = blockIdx.x;
    const int u = threadIdx.x;
    __shared__ float wred[2];

    const float* __restrict__ ypb = yp + (size_t)b * SEQ * TAGS;
    const float* __restrict__ mb  = mask + (size_t)b * SEQ;
    const int*   __restrict__ ytb = yt + (size_t)b * SEQ;

    float sc = 0.f;
#pragma unroll
    for (int k = 0; k < SEQ / TAGS; ++k) {
        int s = u + k * TAGS;
        int l = ytb[s];
        float m = mb[s];
        sc += ypb[s * TAGS + l] * m;
        if (s + 1 < SEQ) {
            int l2 = ytb[s + 1];
            sc += A[l * TAGS + l2] * m * mb[s + 1];
        }
    }
#pragma unroll
    for (int off = 32; off > 0; off >>= 1)
        sc += __shfl_down(sc, off, 64);
    if ((u & 63) == 0) wred[u >> 6] = sc;
    __syncthreads();
    if (u == 0) atomicAdd(out, -(wred[0] + wred[1]) * (1.0f / (float)BATCH));
}

extern "C" void kernel_launch(void* const* d_in, const int* in_sizes, int n_in,
                              void* d_out, int out_size, void* d_ws, size_t ws_size,
                              hipStream_t stream) {
    const float* yp   = (const float*)d_in[0];   // (128,1024,128) f32
    const int*   yt   = (const int*)d_in[1];     // (128,1024) int
    const float* mask = (const float*)d_in[2];   // (128,1024) f32
    const float* A    = (const float*)d_in[3];   // (128,128) f32
    float* out = (float*)d_out;

    unsigned* gs = (unsigned*)d_ws;
    float* Fst = (float*)((char*)d_ws + GS_BYTES);
    float* Vst = Fst + BATCH * TAGS;
    float* Cf  = Vst + BATCH * TAGS;
    float* Cb  = Cf + BATCH;

    (void)hipMemsetAsync(out, 0, sizeof(float), stream);
    crf_score<<<BATCH, TAGS, 0, stream>>>(yp, yt, mask, A, out);
    exp_pack<<<NGRP * SEQ, 64, 0, stream>>>(yp, gs);
    crf_seq<<<2 * NGRP, 128, 0, stream>>>(gs, A, Fst, Vst, Cf, Cb);
    crf_combine<<<1, BATCH, 0, stream>>>(Fst, Vst, Cf, Cb, out);
}

// Round 3
// 320.397 us; speedup vs baseline: 5.0337x; 5.0337x over previous
//
#include <hip/hip_runtime.h>

#define TAGS 128
#define SEQ 1024
#define BATCH 128
#define NGRP 8          // batch groups of 16 (per direction)
#define GB 16           // batches per group

typedef __attribute__((ext_vector_type(8))) _Float16 half8;
typedef __attribute__((ext_vector_type(2))) _Float16 half2v;
typedef __attribute__((ext_vector_type(4))) float f32x4;

#define GS_BYTES ((size_t)NGRP * SEQ * 64 * 16 * 4)   // 33.5 MB of u32 (f16 pairs)

static __device__ __forceinline__ unsigned pk2u(float a, float b) {
    return __builtin_bit_cast(unsigned, __builtin_amdgcn_cvt_pkrtz(a, b));
}

// ---------------------------------------------------------------------------
// Layout (16x16x32 MFMA, 16-batch chains).
// Lane L: n = L&15 (batch col), kb = L>>4 (k-block).
// B-frag / state dword slot (sl in [0,4), d in [0,4)) at lane L holds the f16
// pair for tags u0, u0+1 with  u0 = 16*(2*sl + (d>>1)) + 4*kb + 2*(d&1).
// acc[t][r] (D[m][n], m = 16t + 4kb + r) maps straight into the B-frag slot
// (sl,d) with t = 2sl+(d>>1), r = 2(d&1) -- no cross-lane movement.
// gs memory: per (grp, i, lane): 16 dwords in slot order [sl][d].
// ---------------------------------------------------------------------------

#define EPITCH 66
__global__ __launch_bounds__(64, 1)
void exp_pack(const float* __restrict__ yp, unsigned* __restrict__ gs)
{
    __shared__ unsigned ldsT[GB * EPITCH];
    const int blk = blockIdx.x;               // grp*SEQ + i
    const int grp = blk >> 10, i = blk & (SEQ - 1);
    const int tid = threadIdx.x;
    const float* src = yp + (size_t)(grp * GB) * SEQ * TAGS + (size_t)i * TAGS;

#pragma unroll
    for (int k = 0; k < 8; ++k) {
        int f = tid + 64 * k;                 // flat float4 index in 16x32 grid
        int r = f >> 5, c = f & 31;
        const float4 v = *(const float4*)(src + (size_t)r * SEQ * TAGS + 4 * c);
        uint2 d;
        d.x = pk2u(__expf(v.x), __expf(v.y));
        d.y = pk2u(__expf(v.z), __expf(v.w));
        *(uint2*)&ldsT[r * EPITCH + 2 * c] = d;
    }
    __syncthreads();

    const int kb = tid >> 4, n = tid & 15;
    unsigned* dst = gs + ((size_t)blk * 64 + tid) * 16;
    uint2 w[8];
#pragma unroll
    for (int sl = 0; sl < 4; ++sl)
#pragma unroll
        for (int dd = 0; dd < 2; ++dd) {
            int t = 2 * sl + dd;
            int pu = 8 * t + 2 * kb;          // pair index of u0 = 16t+4kb
            w[2 * sl + dd] = *(const uint2*)&ldsT[n * EPITCH + pu];
        }
#pragma unroll
    for (int q = 0; q < 4; ++q)
        ((uint4*)dst)[q] = make_uint4(w[2 * q].x, w[2 * q].y,
                                      w[2 * q + 1].x, w[2 * q + 1].y);
}

// ---------------------------------------------------------------------------
// Main kernel: 16 blocks x 2 waves, wave role W as a TEMPLATE parameter so
// every pksq index is compile-time (rule #20: runtime-indexed reg arrays go
// to scratch -- R2's 56-VGPR / 7x-slowdown bug).
// Wave W computes output rows t = 4W..4W+3 (16 MFMAs) plus a redundant t=0
// pivot chain (4 MFMAs, fixed sl order 0..3 in BOTH waves so q0/rn are
// bitwise identical). Per step: 8-dword-per-lane LDS exchange of the produced
// B-frag half, double-buffered (parity), ONE __syncthreads. Next step
// consumes own-produced slices first so ds_read latency hides under MFMA.
// Blocks 0-7: forward grp 0-7 (steps 1..512 -> F_512); blocks 8-15: backward
// (1023..513 -> beta_512 = V_513). Meet: Z = F_512 . V_513.
// ---------------------------------------------------------------------------
template<int W>
__device__ __forceinline__ void seq_wave(
    const unsigned* __restrict__ gs, const float* __restrict__ Ain,
    float* __restrict__ Fst, float* __restrict__ Vst,
    float* __restrict__ Cf, float* __restrict__ Cb,
    uint4 (&xbuf)[2][2][2][64])
{
    const int blk = blockIdx.x;
    const bool fwd = blk < NGRP;
    const int grp = fwd ? blk : blk - NGRP;
    const int lane = threadIdx.x & 63;
    const int kb = lane >> 4, n = lane & 15;

    // ---- E A-frags in registers: own 4 row-blocks + pivot (t=0) ----
    auto build_frag = [&](int t, int sl) -> half8 {
        unsigned q[4];
#pragma unroll
        for (int d = 0; d < 4; ++d) {
            int v0 = 16 * (2 * sl + (d >> 1)) + 4 * kb + 2 * (d & 1);
            int m = 16 * t + n;
            float e0, e1;
            if (fwd) { e0 = __expf(Ain[v0 * TAGS + m]);
                       e1 = __expf(Ain[(v0 + 1) * TAGS + m]); }
            else     { e0 = __expf(Ain[m * TAGS + v0]);
                       e1 = __expf(Ain[m * TAGS + v0 + 1]); }
            q[d] = pk2u(e0, e1);
        }
        uint4 qv = make_uint4(q[0], q[1], q[2], q[3]);
        return __builtin_bit_cast(half8, qv);
    };
    half8 afO[4][4], af0[4];
#pragma unroll
    for (int tt = 0; tt < 4; ++tt)
#pragma unroll
        for (int sl = 0; sl < 4; ++sl)
            afO[tt][sl] = build_frag(4 * W + tt, sl);
#pragma unroll
    for (int sl = 0; sl < 4; ++sl)
        af0[sl] = build_frag(0, sl);

    // ---- init state from G_0 (fwd) / G_1023 (bwd): pack IS the B-frag ----
    uint4 pksq[4];
    {
        const uint4* g0 = (const uint4*)(gs +
            ((size_t)(grp * SEQ + (fwd ? 0 : SEQ - 1)) * 64 + lane) * 16);
#pragma unroll
        for (int k2 = 0; k2 < 4; ++k2) pksq[k2] = g0[k2];
    }
    float C = 0.f;
    f32x4 accO[4], a0;
    uint4 ghA[2], ghB[2];

    auto load_gh = [&](uint4 (&gq)[2], int idx) {
        const uint4* p = (const uint4*)(gs +
            ((size_t)(grp * SEQ + idx) * 64 + lane) * 16) + 2 * W;
        gq[0] = p[0]; gq[1] = p[1];
    };

    auto mfma_only = [&]() {
        f32x4 z = {0.f, 0.f, 0.f, 0.f};
#pragma unroll
        for (int slq = 0; slq < 4; ++slq) {
            constexpr int base = 2 * W;
            const int sl = (slq + base) & 3;  // compile-time after unroll
            half8 bf = __builtin_bit_cast(half8, pksq[sl]);
#pragma unroll
            for (int tt = 0; tt < 4; ++tt)
                accO[tt] = __builtin_amdgcn_mfma_f32_16x16x32_f16(
                    afO[tt][sl], bf, slq == 0 ? z : accO[tt], 0, 0, 0);
            // pivot chain in FIXED order sl=0..3 (bitwise-equal across waves)
            half8 bfp = __builtin_bit_cast(half8, pksq[slq]);
            a0 = __builtin_amdgcn_mfma_f32_16x16x32_f16(
                af0[slq], bfp, slq == 0 ? z : a0, 0, 0, 0);
        }
    };

    // step: mfma + epi(own half) + LDS exchange (one barrier, parity dbuf)
    auto step = [&](const uint4 (&gh)[2], int pb) {
        mfma_only();
        float q0 = __shfl(a0[0], n, 64);      // D[0][n] lives in lane n
        float rn = __builtin_amdgcn_rcpf(q0) * 0.0625f;   // 2^-4 headroom
        C += __logf(q0) + 2.7725887222397812f;            // + log(16)
        const unsigned* gu = (const unsigned*)gh;
        unsigned pko[8];
#pragma unroll
        for (int s2 = 0; s2 < 2; ++s2)
#pragma unroll
            for (int d = 0; d < 4; ++d) {
                int tt = 2 * s2 + (d >> 1), r = 2 * (d & 1);
                half2v hv = __builtin_bit_cast(half2v,
                    pk2u(accO[tt][r] * rn, accO[tt][r + 1] * rn));
                half2v g2 = __builtin_bit_cast(half2v, gu[4 * s2 + d]);
                hv = hv * g2;
                pko[4 * s2 + d] = __builtin_bit_cast(unsigned, hv);
            }
        uint4 o0 = make_uint4(pko[0], pko[1], pko[2], pko[3]);
        uint4 o1 = make_uint4(pko[4], pko[5], pko[6], pko[7]);
        pksq[2 * W]     = o0;                 // compile-time indices
        pksq[2 * W + 1] = o1;
        xbuf[pb][W][0][lane] = o0;            // 16B/lane contiguous: conflict-free
        xbuf[pb][W][1][lane] = o1;
        __syncthreads();
        pksq[2 * (1 - W)]     = xbuf[pb][1 - W][0][lane];
        pksq[2 * (1 - W) + 1] = xbuf[pb][1 - W][1][lane];
    };

    if (fwd) {
        load_gh(ghA, 1); load_gh(ghB, 2);
#pragma unroll 1
        for (int j = 1; j <= 509; j += 2) {   // steps 1..510
            step(ghA, 1); load_gh(ghA, j + 2);
            step(ghB, 0); load_gh(ghB, j + 3);
        }
        step(ghA, 1);                         // step 511 (ghA = G_511)
        mfma_only();                          // peeled step 512
        {
            float q0 = __shfl(a0[0], n, 64);
            float rn = __builtin_amdgcn_rcpf(q0);
            C += __logf(q0);
            const unsigned* gu = (const unsigned*)ghB;   // G_512 own half
            const int b = grp * GB + n;
#pragma unroll
            for (int s2 = 0; s2 < 2; ++s2)
#pragma unroll
                for (int dd = 0; dd < 2; ++dd) {
                    const int tt = 2 * s2 + dd, t = 4 * W + tt;
                    half2v ga = __builtin_bit_cast(half2v, gu[4 * s2 + 2 * dd]);
                    half2v gb = __builtin_bit_cast(half2v, gu[4 * s2 + 2 * dd + 1]);
                    float4 wv;
                    wv.x = accO[tt][0] * rn * (float)ga[0];
                    wv.y = accO[tt][1] * rn * (float)ga[1];
                    wv.z = accO[tt][2] * rn * (float)gb[0];
                    wv.w = accO[tt][3] * rn * (float)gb[1];
                    *(float4*)&Fst[(size_t)b * TAGS + 16 * t + 4 * kb] = wv;
                }
            if (W == 0 && kb == 0) Cf[b] = C;
        }
    } else {
        load_gh(ghA, 1022); load_gh(ghB, 1021);
#pragma unroll 1
        for (int j = 1; j <= 507; j += 2) {   // epis G_1022..G_515
            step(ghA, 1); load_gh(ghA, 1023 - (j + 2));
            step(ghB, 0); load_gh(ghB, 1023 - (j + 3));
        }
        step(ghA, 1);                         // epi G_514
        step(ghB, 0);                         // epi G_513
        mfma_only();                          // peeled: beta_512
        {
            float q0 = __shfl(a0[0], n, 64);
            float rn = __builtin_amdgcn_rcpf(q0);
            C += __logf(q0);
            const int b = grp * GB + n;
#pragma unroll
            for (int tt = 0; tt < 4; ++tt) {
                const int t = 4 * W + tt;
                float4 wv;
                wv.x = accO[tt][0] * rn; wv.y = accO[tt][1] * rn;
                wv.z = accO[tt][2] * rn; wv.w = accO[tt][3] * rn;
                *(float4*)&Vst[(size_t)b * TAGS + 16 * t + 4 * kb] = wv;
            }
            if (W == 0 && kb == 0) Cb[b] = C;
        }
    }
}

__global__ __launch_bounds__(128, 1)
void crf_seq(const unsigned* __restrict__ gs, const float* __restrict__ Ain,
             float* __restrict__ Fst, float* __restrict__ Vst,
             float* __restrict__ Cf, float* __restrict__ Cb)
{
    __shared__ uint4 xbuf[2][2][2][64];       // [parity][half][quad][lane]
    if (threadIdx.x < 64)
        seq_wave<0>(gs, Ain, Fst, Vst, Cf, Cb, xbuf);
    else
        seq_wave<1>(gs, Ain, Fst, Vst, Cf, Cb, xbuf);
}

// logZ_b = Cf + Cb + log(F_512 . V_513);  out += logZ_b / BATCH
__global__ __launch_bounds__(128, 1)
void crf_combine(const float* __restrict__ Fst, const float* __restrict__ Vst,
                 const float* __restrict__ Cf, const float* __restrict__ Cb,
                 float* __restrict__ out)
{
    int b = threadIdx.x;
    const float* f = Fst + (size_t)b * TAGS;
    const float* v = Vst + (size_t)b * TAGS;
    float s = 0.f;
#pragma unroll
    for (int u = 0; u < TAGS; ++u) s += f[u] * v[u];
    float logZ = Cf[b] + Cb[b] + __logf(s);
    atomicAdd(out, logZ * (1.0f / (float)BATCH));
}

// Gold-path score (validated): adds -score_b / BATCH
__global__ __launch_bounds__(128, 1)
void crf_score(const float* __restrict__ yp, const int* __restrict__ yt,
               const float* __restrict__ mask, const float* __restrict__ A,
               float* __restrict__ out)
{
    const int b = blockIdx.x;
    const int u = threadIdx.x;
    __shared__ float wred[2];

    const float* __restrict__ ypb = yp + (size_t)b * SEQ * TAGS;
    const float* __restrict__ mb  = mask + (size_t)b * SEQ;
    const int*   __restrict__ ytb = yt + (size_t)b * SEQ;

    float sc = 0.f;
#pragma unroll
    for (int k = 0; k < SEQ / TAGS; ++k) {
        int s = u + k * TAGS;
        int l = ytb[s];
        float m = mb[s];
        sc += ypb[s * TAGS + l] * m;
        if (s + 1 < SEQ) {
            int l2 = ytb[s + 1];
            sc += A[l * TAGS + l2] * m * mb[s + 1];
        }
    }
#pragma unroll
    for (int off = 32; off > 0; off >>= 1)
        sc += __shfl_down(sc, off, 64);
    if ((u & 63) == 0) wred[u >> 6] = sc;
    __syncthreads();
    if (u == 0) atomicAdd(out, -(wred[0] + wred[1]) * (1.0f / (float)BATCH));
}

extern "C" void kernel_launch(void* const* d_in, const int* in_sizes, int n_in,
                              void* d_out, int out_size, void* d_ws, size_t ws_size,
                              hipStream_t stream) {
    const float* yp   = (const float*)d_in[0];   // (128,1024,128) f32
    const int*   yt   = (const int*)d_in[1];     // (128,1024) int
    const float* mask = (const float*)d_in[2];   // (128,1024) f32
    const float* A    = (const float*)d_in[3];   // (128,128) f32
    float* out = (float*)d_out;

    unsigned* gs = (unsigned*)d_ws;
    float* Fst = (float*)((char*)d_ws + GS_BYTES);
    float* Vst = Fst + BATCH * TAGS;
    float* Cf  = Vst + BATCH * TAGS;
    float* Cb  = Cf + BATCH;

    (void)hipMemsetAsync(out, 0, sizeof(float), stream);
    crf_score<<<BATCH, TAGS, 0, stream>>>(yp, yt, mask, A, out);
    exp_pack<<<NGRP * SEQ, 64, 0, stream>>>(yp, gs);
    crf_seq<<<2 * NGRP, 128, 0, stream>>>(gs, A, Fst, Vst, Cf, Cb);
    crf_combine<<<1, BATCH, 0, stream>>>(Fst, Vst, Cf, Cb, out);
}

// Round 4
// 277.417 us; speedup vs baseline: 5.8136x; 1.1549x over previous
//
#include <hip/hip_runtime.h>

#define TAGS 128
#define SEQ 1024
#define BATCH 128
#define NGRP 8          // batch groups of 16 (per direction)
#define GB 16           // batches per group

typedef __attribute__((ext_vector_type(8))) _Float16 half8;
typedef __attribute__((ext_vector_type(2))) _Float16 half2v;
typedef __attribute__((ext_vector_type(4))) float f32x4;

#define GS_BYTES ((size_t)NGRP * SEQ * 64 * 16 * 4)   // 33.5 MB of u32 (f16 pairs)

static __device__ __forceinline__ unsigned pk2u(float a, float b) {
    return __builtin_bit_cast(unsigned, __builtin_amdgcn_cvt_pkrtz(a, b));
}

// ---------------------------------------------------------------------------
// Layout (16x16x32 MFMA, 16-batch chains).
// Lane L: n = L&15 (batch col), kb = L>>4 (k-block).
// B-frag / state dword slot (sl in [0,4), d in [0,4)) at lane L holds the f16
// pair for tags u0, u0+1 with  u0 = 16*(2*sl + (d>>1)) + 4*kb + 2*(d&1).
// acc[t][r] (D[m][n], m = 16t + 4kb + r) maps into slot (sl,d) with
// t = 2sl+(d>>1), r = 2(d&1) -- so row-block pair {2sl, 2sl+1} produces
// exactly slice sl: wave W owns rows {2W, 2W+1} and produces slice W.
// gs memory: per (grp, i, lane): 16 dwords in slot order [sl][d].
// ---------------------------------------------------------------------------

#define EPITCH 66
__global__ __launch_bounds__(256, 1)
void exp_pack(const float* __restrict__ yp, unsigned* __restrict__ gs)
{
    __shared__ unsigned ldsT[4][GB * EPITCH];
    const int wv = threadIdx.x >> 6, tid = threadIdx.x & 63;
    const int blk4 = blockIdx.x;              // grp*(SEQ/4) + i4
    const int grp = blk4 >> 8;
    const int i = ((blk4 & 255) << 2) | wv;
    const float* src = yp + (size_t)(grp * GB) * SEQ * TAGS + (size_t)i * TAGS;

#pragma unroll
    for (int k = 0; k < 8; ++k) {
        int f = tid + 64 * k;                 // flat float4 index in 16x32 grid
        int r = f >> 5, c = f & 31;
        const float4 v = *(const float4*)(src + (size_t)r * SEQ * TAGS + 4 * c);
        uint2 d;
        d.x = pk2u(__expf(v.x), __expf(v.y));
        d.y = pk2u(__expf(v.z), __expf(v.w));
        *(uint2*)&ldsT[wv][r * EPITCH + 2 * c] = d;
    }
    __syncthreads();

    const int kb = tid >> 4, n = tid & 15;
    unsigned* dst = gs + ((size_t)(grp * SEQ + i) * 64 + tid) * 16;
    uint2 w[8];
#pragma unroll
    for (int sl = 0; sl < 4; ++sl)
#pragma unroll
        for (int dd = 0; dd < 2; ++dd) {
            int t = 2 * sl + dd;
            int pu = 8 * t + 2 * kb;          // pair index of u0 = 16t+4kb
            w[2 * sl + dd] = *(const uint2*)&ldsT[wv][n * EPITCH + pu];
        }
#pragma unroll
    for (int q = 0; q < 4; ++q)
        ((uint4*)dst)[q] = make_uint4(w[2 * q].x, w[2 * q].y,
                                      w[2 * q + 1].x, w[2 * q + 1].y);
}

// ---------------------------------------------------------------------------
// Main kernel: 16 blocks x 4 waves, wave role W as TEMPLATE param (rule #20:
// all state indices compile-time). Wave W computes rows t = 2W, 2W+1 (8 MFMA,
// two depth-2 chains + f32 add) and produces state slice W. Pivot (row 0):
// fixed pairing e=(sl0,sl1), o=(sl2,sl3), q0 = e+o -- bitwise identical in
// every wave (shared scale rn). Wave 0's own chains ARE the pivot (cA/cB =
// e/o), waves 1-3 run a 4-MFMA pivot block issued AFTER their own rows so the
// exchanged-slice ds_reads are complete. Per step: one uint4/lane LDS
// exchange (parity double-buffer), ONE __syncthreads.
// Blocks 0-7: forward grp 0-7 (steps 1..512 -> F_512); blocks 8-15: backward
// (1023..513 -> beta_512 = V_513). Meet: Z = F_512 . V_513.
// ---------------------------------------------------------------------------
template<int W>
__device__ __forceinline__ void seq_wave(
    const unsigned* __restrict__ gs, const float* __restrict__ Ain,
    float* __restrict__ Fst, float* __restrict__ Vst,
    float* __restrict__ Cf, float* __restrict__ Cb,
    uint4 (&xbuf)[2][4][64])
{
    const int blk = blockIdx.x;
    const bool fwd = blk < NGRP;
    const int grp = fwd ? blk : blk - NGRP;
    const int lane = threadIdx.x & 63;
    const int kb = lane >> 4, n = lane & 15;

    // chain pairing: own slice first, exchanged slices late
    constexpr int cA0 = W, cA1 = (W + 1) & 3, cB0 = (W + 2) & 3, cB1 = (W + 3) & 3;

    auto build_frag = [&](int t, int sl) -> half8 {
        unsigned q[4];
#pragma unroll
        for (int d = 0; d < 4; ++d) {
            int v0 = 16 * (2 * sl + (d >> 1)) + 4 * kb + 2 * (d & 1);
            int m = 16 * t + n;
            float e0, e1;
            if (fwd) { e0 = __expf(Ain[v0 * TAGS + m]);
                       e1 = __expf(Ain[(v0 + 1) * TAGS + m]); }
            else     { e0 = __expf(Ain[m * TAGS + v0]);
                       e1 = __expf(Ain[m * TAGS + v0 + 1]); }
            q[d] = pk2u(e0, e1);
        }
        uint4 qv = make_uint4(q[0], q[1], q[2], q[3]);
        return __builtin_bit_cast(half8, qv);
    };
    half8 afO[2][4];                          // own rows t = 2W, 2W+1
#pragma unroll
    for (int tt = 0; tt < 2; ++tt)
#pragma unroll
        for (int sl = 0; sl < 4; ++sl)
            afO[tt][sl] = build_frag(2 * W + tt, sl);
    half8 af0[4];                             // pivot row-block (waves 1-3)
    if (W != 0)
#pragma unroll
        for (int sl = 0; sl < 4; ++sl)
            af0[sl] = build_frag(0, sl);

    // ---- init state from G_0 (fwd) / G_1023 (bwd): pack IS the B-frag ----
    uint4 pksq[4];
    {
        const uint4* g0 = (const uint4*)(gs +
            ((size_t)(grp * SEQ + (fwd ? 0 : SEQ - 1)) * 64 + lane) * 16);
#pragma unroll
        for (int k2 = 0; k2 < 4; ++k2) pksq[k2] = g0[k2];
    }
    float C = 0.f;
    f32x4 acc[2], a0;
    uint4 ghA, ghB;

    // per-(pos,lane) G quarter: uint4 index = (grp*SEQ+idx)*256 + lane*4 + W
    const uint4* gbase = (const uint4*)gs + ((size_t)grp * SEQ * 256 + lane * 4 + W);
    auto load_gh = [&](uint4& g, int idx) { g = gbase[(size_t)idx * 256]; };

    auto mfma_all = [&]() {
        f32x4 z = {0.f, 0.f, 0.f, 0.f};
        half8 bA0 = __builtin_bit_cast(half8, pksq[cA0]);
        half8 bA1 = __builtin_bit_cast(half8, pksq[cA1]);
        half8 bB0 = __builtin_bit_cast(half8, pksq[cB0]);
        half8 bB1 = __builtin_bit_cast(half8, pksq[cB1]);
        f32x4 aA[2], aB[2];
#pragma unroll
        for (int tt = 0; tt < 2; ++tt) {
            aA[tt] = __builtin_amdgcn_mfma_f32_16x16x32_f16(afO[tt][cA0], bA0, z, 0, 0, 0);
            aB[tt] = __builtin_amdgcn_mfma_f32_16x16x32_f16(afO[tt][cB0], bB0, z, 0, 0, 0);
        }
#pragma unroll
        for (int tt = 0; tt < 2; ++tt) {
            aA[tt] = __builtin_amdgcn_mfma_f32_16x16x32_f16(afO[tt][cA1], bA1, aA[tt], 0, 0, 0);
            aB[tt] = __builtin_amdgcn_mfma_f32_16x16x32_f16(afO[tt][cB1], bB1, aB[tt], 0, 0, 0);
        }
        if (W == 0) {
            // own chains ARE the pivot pairing e=(0,1), o=(2,3)
#pragma unroll
            for (int tt = 0; tt < 2; ++tt) acc[tt] = aA[tt] + aB[tt];
            a0 = acc[0];
        } else {
            // pivot block issued after own rows; fixed order e=(0,1), o=(2,3)
            half8 p0 = __builtin_bit_cast(half8, pksq[0]);
            half8 p1 = __builtin_bit_cast(half8, pksq[1]);
            half8 p2 = __builtin_bit_cast(half8, pksq[2]);
            half8 p3 = __builtin_bit_cast(half8, pksq[3]);
            f32x4 pe = __builtin_amdgcn_mfma_f32_16x16x32_f16(af0[0], p0, z, 0, 0, 0);
            f32x4 po = __builtin_amdgcn_mfma_f32_16x16x32_f16(af0[2], p2, z, 0, 0, 0);
            pe = __builtin_amdgcn_mfma_f32_16x16x32_f16(af0[1], p1, pe, 0, 0, 0);
            po = __builtin_amdgcn_mfma_f32_16x16x32_f16(af0[3], p3, po, 0, 0, 0);
#pragma unroll
            for (int tt = 0; tt < 2; ++tt) acc[tt] = aA[tt] + aB[tt];
            a0 = pe + po;
        }
    };

    // step: mfma + epi(own slice) + LDS exchange (one barrier, parity dbuf)
    auto step = [&](const uint4& gh, int pb) {
        mfma_all();
        float q0 = __shfl(a0[0], n, 64);      // D[0][n] lives in lane n
        float rn = __builtin_amdgcn_rcpf(q0) * 0.0625f;   // 2^-4 headroom
        C += __logf(q0) + 2.7725887222397812f;            // + log(16)
        const unsigned* gu = (const unsigned*)&gh;
        unsigned pko[4];
#pragma unroll
        for (int d = 0; d < 4; ++d) {
            int tt = d >> 1, r = 2 * (d & 1);
            half2v hv = __builtin_bit_cast(half2v,
                pk2u(acc[tt][r] * rn, acc[tt][r + 1] * rn));
            half2v g2 = __builtin_bit_cast(half2v, gu[d]);
            hv = hv * g2;
            pko[d] = __builtin_bit_cast(unsigned, hv);
        }
        uint4 o0 = make_uint4(pko[0], pko[1], pko[2], pko[3]);
        pksq[W] = o0;                         // compile-time index
        xbuf[pb][W][lane] = o0;               // 16B/lane contiguous: conflict-free
        __syncthreads();
#pragma unroll
        for (int s = 0; s < 4; ++s)
            if (s != W) pksq[s] = xbuf[pb][s][lane];
    };

    if (fwd) {
        load_gh(ghA, 1); load_gh(ghB, 2);
#pragma unroll 1
        for (int j = 1; j <= 509; j += 2) {   // steps 1..510
            step(ghA, 1); load_gh(ghA, j + 2);
            step(ghB, 0); load_gh(ghB, j + 3);
        }
        step(ghA, 1);                         // step 511 (ghA = G_511)
        mfma_all();                           // peeled step 512
        {
            float q0 = __shfl(a0[0], n, 64);
            float rn = __builtin_amdgcn_rcpf(q0);
            C += __logf(q0);
            const unsigned* gu = (const unsigned*)&ghB;  // G_512 own quarter
            const int b = grp * GB + n;
#pragma unroll
            for (int tt = 0; tt < 2; ++tt) {
                const int t = 2 * W + tt;
                half2v ga = __builtin_bit_cast(half2v, gu[2 * tt]);
                half2v gb = __builtin_bit_cast(half2v, gu[2 * tt + 1]);
                float4 wv;
                wv.x = acc[tt][0] * rn * (float)ga[0];
                wv.y = acc[tt][1] * rn * (float)ga[1];
                wv.z = acc[tt][2] * rn * (float)gb[0];
                wv.w = acc[tt][3] * rn * (float)gb[1];
                *(float4*)&Fst[(size_t)b * TAGS + 16 * t + 4 * kb] = wv;
            }
            if (W == 0 && kb == 0) Cf[b] = C;
        }
    } else {
        load_gh(ghA, 1022); load_gh(ghB, 1021);
#pragma unroll 1
        for (int j = 1; j <= 507; j += 2) {   // epis G_1022..G_515
            step(ghA, 1); load_gh(ghA, 1023 - (j + 2));
            step(ghB, 0); load_gh(ghB, 1023 - (j + 3));
        }
        step(ghA, 1);                         // epi G_514
        step(ghB, 0);                         // epi G_513
        mfma_all();                           // peeled: beta_512
        {
            float q0 = __shfl(a0[0], n, 64);
            float rn = __builtin_amdgcn_rcpf(q0);
            C += __logf(q0);
            const int b = grp * GB + n;
#pragma unroll
            for (int tt = 0; tt < 2; ++tt) {
                const int t = 2 * W + tt;
                float4 wv;
                wv.x = acc[tt][0] * rn; wv.y = acc[tt][1] * rn;
                wv.z = acc[tt][2] * rn; wv.w = acc[tt][3] * rn;
                *(float4*)&Vst[(size_t)b * TAGS + 16 * t + 4 * kb] = wv;
            }
            if (W == 0 && kb == 0) Cb[b] = C;
        }
    }
}

__global__ __launch_bounds__(256, 1)
void crf_seq(const unsigned* __restrict__ gs, const float* __restrict__ Ain,
             float* __restrict__ Fst, float* __restrict__ Vst,
             float* __restrict__ Cf, float* __restrict__ Cb)
{
    __shared__ uint4 xbuf[2][4][64];          // [parity][slice][lane]
    const int w = threadIdx.x >> 6;
    if      (w == 0) seq_wave<0>(gs, Ain, Fst, Vst, Cf, Cb, xbuf);
    else if (w == 1) seq_wave<1>(gs, Ain, Fst, Vst, Cf, Cb, xbuf);
    else if (w == 2) seq_wave<2>(gs, Ain, Fst, Vst, Cf, Cb, xbuf);
    else             seq_wave<3>(gs, Ain, Fst, Vst, Cf, Cb, xbuf);
}

// logZ_b = Cf + Cb + log(F_512 . V_513);  out += logZ_b / BATCH
__global__ __launch_bounds__(128, 1)
void crf_combine(const float* __restrict__ Fst, const float* __restrict__ Vst,
                 const float* __restrict__ Cf, const float* __restrict__ Cb,
                 float* __restrict__ out)
{
    int b = threadIdx.x;
    const float* f = Fst + (size_t)b * TAGS;
    const float* v = Vst + (size_t)b * TAGS;
    float s = 0.f;
#pragma unroll
    for (int u = 0; u < TAGS; ++u) s += f[u] * v[u];
    float logZ = Cf[b] + Cb[b] + __logf(s);
    atomicAdd(out, logZ * (1.0f / (float)BATCH));
}

// Gold-path score (validated): adds -score_b / BATCH
__global__ __launch_bounds__(128, 1)
void crf_score(const float* __restrict__ yp, const int* __restrict__ yt,
               const float* __restrict__ mask, const float* __restrict__ A,
               float* __restrict__ out)
{
    const int b = blockIdx.x;
    const int u = threadIdx.x;
    __shared__ float wred[2];

    const float* __restrict__ ypb = yp + (size_t)b * SEQ * TAGS;
    const float* __restrict__ mb  = mask + (size_t)b * SEQ;
    const int*   __restrict__ ytb = yt + (size_t)b * SEQ;

    float sc = 0.f;
#pragma unroll
    for (int k = 0; k < SEQ / TAGS; ++k) {
        int s = u + k * TAGS;
        int l = ytb[s];
        float m = mb[s];
        sc += ypb[s * TAGS + l] * m;
        if (s + 1 < SEQ) {
            int l2 = ytb[s + 1];
            sc += A[l * TAGS + l2] * m * mb[s + 1];
        }
    }
#pragma unroll
    for (int off = 32; off > 0; off >>= 1)
        sc += __shfl_down(sc, off, 64);
    if ((u & 63) == 0) wred[u >> 6] = sc;
    __syncthreads();
    if (u == 0) atomicAdd(out, -(wred[0] + wred[1]) * (1.0f / (float)BATCH));
}

extern "C" void kernel_launch(void* const* d_in, const int* in_sizes, int n_in,
                              void* d_out, int out_size, void* d_ws, size_t ws_size,
                              hipStream_t stream) {
    const float* yp   = (const float*)d_in[0];   // (128,1024,128) f32
    const int*   yt   = (const int*)d_in[1];     // (128,1024) int
    const float* mask = (const float*)d_in[2];   // (128,1024) f32
    const float* A    = (const float*)d_in[3];   // (128,128) f32
    float* out = (float*)d_out;

    unsigned* gs = (unsigned*)d_ws;
    float* Fst = (float*)((char*)d_ws + GS_BYTES);
    float* Vst = Fst + BATCH * TAGS;
    float* Cf  = Vst + BATCH * TAGS;
    float* Cb  = Cf + BATCH;

    (void)hipMemsetAsync(out, 0, sizeof(float), stream);
    crf_score<<<BATCH, TAGS, 0, stream>>>(yp, yt, mask, A, out);
    exp_pack<<<NGRP * SEQ / 4, 256, 0, stream>>>(yp, gs);
    crf_seq<<<2 * NGRP, 256, 0, stream>>>(gs, A, Fst, Vst, Cf, Cb);
    crf_combine<<<1, BATCH, 0, stream>>>(Fst, Vst, Cf, Cb, out);
}